// Round 1
// baseline (2390.837 us; speedup 1.0000x reference)
//
#include <hip/hip_runtime.h>
#include <hip/hip_bf16.h>

#define D 128

// ---------------- degree / norm ----------------
__global__ __launch_bounds__(256) void k_init_deg(float* deg, int n) {
    int i = blockIdx.x * 256 + threadIdx.x;
    if (i < n) deg[i] = 1.0f;   // self-loop contributes 1
}

__global__ __launch_bounds__(256) void k_count_deg(const int* __restrict__ dst,
                                                   float* deg, int e) {
    int i = blockIdx.x * 256 + threadIdx.x;
    if (i < e) unsafeAtomicAdd(&deg[dst[i]], 1.0f);
}

__global__ __launch_bounds__(256) void k_rsqrt(float* deg, int n) {
    int i = blockIdx.x * 256 + threadIdx.x;
    if (i < n) deg[i] = rsqrtf(deg[i]);   // deg >= 1 always (self-loops)
}

// ---------------- SGEMM: C[M x 128] = A[M x 128] @ W[128 x 128] (+bias) ----------------
// 128x128 block tile, BK=16, 256 threads, 8x8 microtile per thread.
#define BM 128
#define BN 128
#define BK 16
#define TM 8
#define TN 8

__global__ __launch_bounds__(256) void k_sgemm(const float* __restrict__ A,
                                               const float* __restrict__ W,
                                               const float* __restrict__ bias,
                                               float* __restrict__ C, int M) {
    __shared__ float As[BK][BM];       // x tile, transposed: As[k][m]
    __shared__ float Bs[BK][BN];       // W tile: Bs[k][n]

    const int tid = threadIdx.x;
    const int row0 = blockIdx.x * BM;
    const int tx = tid & 15;           // 16 cols of threads
    const int ty = tid >> 4;           // 16 rows of threads

    float acc[TM][TN] = {};

    for (int k0 = 0; k0 < D; k0 += BK) {
        // stage A tile (transposed into LDS). 128 rows x 16 k = 512 float4.
        #pragma unroll
        for (int i = 0; i < 2; ++i) {
            int r = (tid >> 2) + i * 64;
            int c = (tid & 3) * 4;
            int rr = row0 + r; if (rr >= M) rr = M - 1;   // clamp (values unused for OOB rows)
            const float4 v = *(const float4*)(A + (size_t)rr * D + k0 + c);
            As[c + 0][r] = v.x; As[c + 1][r] = v.y; As[c + 2][r] = v.z; As[c + 3][r] = v.w;
        }
        // stage W tile: 16 rows x 128 = 512 float4, layout matches global.
        #pragma unroll
        for (int i = 0; i < 2; ++i) {
            int idx = tid + i * 256;
            int rk = idx >> 5;
            int cc = (idx & 31) * 4;
            *(float4*)&Bs[rk][cc] = *(const float4*)(W + (size_t)(k0 + rk) * D + cc);
        }
        __syncthreads();

        #pragma unroll
        for (int kk = 0; kk < BK; ++kk) {
            float a[TM], b[TN];
            #pragma unroll
            for (int i = 0; i < TM; i += 4)
                *(float4*)&a[i] = *(const float4*)&As[kk][ty * TM + i];
            #pragma unroll
            for (int j = 0; j < TN; j += 4)
                *(float4*)&b[j] = *(const float4*)&Bs[kk][tx * TN + j];
            #pragma unroll
            for (int i = 0; i < TM; ++i)
                #pragma unroll
                for (int j = 0; j < TN; ++j)
                    acc[i][j] += a[i] * b[j];
        }
        __syncthreads();
    }

    // epilogue
    #pragma unroll
    for (int i = 0; i < TM; ++i) {
        int r = row0 + ty * TM + i;
        if (r >= M) continue;
        #pragma unroll
        for (int j = 0; j < TN; j += 4) {
            int cc = tx * TN + j;
            float4 v = *(float4*)&acc[i][j];
            if (bias) {
                float4 bv = *(const float4*)(bias + cc);
                v.x += bv.x; v.y += bv.y; v.z += bv.z; v.w += bv.w;
            }
            *(float4*)(C + (size_t)r * D + cc) = v;
        }
    }
}

// ---------------- edge scatter: acc[dst] += h[src] * dinv[src]*dinv[dst] ----------------
// 32 lanes per edge, float4 per lane (128 floats).
__global__ __launch_bounds__(256) void k_scatter(const int* __restrict__ src,
                                                 const int* __restrict__ dst,
                                                 const float* __restrict__ dinv,
                                                 const float* __restrict__ h,
                                                 float* __restrict__ acc, int E) {
    const int g = threadIdx.x >> 5;
    const int lane = threadIdx.x & 31;
    const int e = blockIdx.x * 8 + g;
    if (e >= E) return;
    const int s = src[e];
    const int d = dst[e];
    const float c = dinv[s] * dinv[d];
    const float4 v = *(const float4*)(h + (size_t)s * D + lane * 4);
    float* p = acc + (size_t)d * D + lane * 4;
    unsafeAtomicAdd(p + 0, v.x * c);
    unsafeAtomicAdd(p + 1, v.y * c);
    unsafeAtomicAdd(p + 2, v.z * c);
    unsafeAtomicAdd(p + 3, v.w * c);
}

// ---------------- finalize: out = relu(acc + h*dinv^2 + b) [+ res] ----------------
__global__ __launch_bounds__(256) void k_finalize(const float* __restrict__ acc,
                                                  const float* __restrict__ h,
                                                  const float* __restrict__ dinv,
                                                  const float* __restrict__ bias,
                                                  const float* __restrict__ res,
                                                  float* __restrict__ out, int n4) {
    int idx = blockIdx.x * 256 + threadIdx.x;   // float4 index over N*32
    if (idx >= n4) return;
    int row = idx >> 5;
    int c4 = (idx & 31) * 4;
    float di = dinv[row];
    float self = di * di;
    float4 a = *(const float4*)(acc + (size_t)idx * 4);
    float4 hv = *(const float4*)(h + (size_t)idx * 4);
    float4 bv = *(const float4*)(bias + c4);
    float4 o;
    o.x = fmaxf(a.x + hv.x * self + bv.x, 0.0f);
    o.y = fmaxf(a.y + hv.y * self + bv.y, 0.0f);
    o.z = fmaxf(a.z + hv.z * self + bv.z, 0.0f);
    o.w = fmaxf(a.w + hv.w * self + bv.w, 0.0f);
    if (res) {
        float4 rv = *(const float4*)(res + (size_t)idx * 4);
        o.x += rv.x; o.y += rv.y; o.z += rv.z; o.w += rv.w;
    }
    *(float4*)(out + (size_t)idx * 4) = o;
}

extern "C" void kernel_launch(void* const* d_in, const int* in_sizes, int n_in,
                              void* d_out, int out_size, void* d_ws, size_t ws_size,
                              hipStream_t stream) {
    const int N = in_sizes[0] / D;     // 100000
    const int E = in_sizes[1] / 2;     // 600000

    const float* x   = (const float*)d_in[0];
    const int*   ei  = (const int*)d_in[1];
    const int*   src = ei;
    const int*   dst = ei + E;
    const float* W1  = (const float*)d_in[2];
    const float* b1  = (const float*)d_in[3];
    const float* W2  = (const float*)d_in[4];
    const float* b2  = (const float*)d_in[5];
    const float* Wfc = (const float*)d_in[6];
    const float* bfc = (const float*)d_in[7];
    float* out = (float*)d_out;

    // workspace layout
    char* ws = (char*)d_ws;
    float* dinv = (float*)ws;
    size_t hOff = (((size_t)N * 4 + 255) / 256) * 256;
    float* h   = (float*)(ws + hOff);
    float* acc = (float*)(ws + hOff + (size_t)N * D * 4);

    const int nBlk  = (N + 255) / 256;
    const int eBlk  = (E + 255) / 256;
    const int gBlk  = (N + BM - 1) / BM;
    const int sBlk  = (E + 7) / 8;
    const int fBlk  = (N * 32 + 255) / 256;

    // degrees -> dinv
    k_init_deg<<<nBlk, 256, 0, stream>>>(dinv, N);
    k_count_deg<<<eBlk, 256, 0, stream>>>(dst, dinv, E);
    k_rsqrt<<<nBlk, 256, 0, stream>>>(dinv, N);

    // h1 = x @ W1 ; res = x @ Wfc + bfc (into d_out)
    k_sgemm<<<gBlk, 256, 0, stream>>>(x, W1, nullptr, h, N);
    k_sgemm<<<gBlk, 256, 0, stream>>>(x, Wfc, bfc, out, N);

    // layer 1 aggregate
    hipMemsetAsync(acc, 0, (size_t)N * D * 4, stream);
    k_scatter<<<sBlk, 256, 0, stream>>>(src, dst, dinv, h, acc, E);
    // h1b = relu(acc + h*dinv^2 + b1)  (in place into acc)
    k_finalize<<<fBlk, 256, 0, stream>>>(acc, h, dinv, b1, nullptr, acc, N * 32);

    // h2 = h1b @ W2
    k_sgemm<<<gBlk, 256, 0, stream>>>(acc, W2, nullptr, h, N);

    // layer 2 aggregate
    hipMemsetAsync(acc, 0, (size_t)N * D * 4, stream);
    k_scatter<<<sBlk, 256, 0, stream>>>(src, dst, dinv, h, acc, E);
    // out = relu(acc + h*dinv^2 + b2) + res(d_out)
    k_finalize<<<fBlk, 256, 0, stream>>>(acc, h, dinv, b2, out, out, N * 32);
}

// Round 2
// 442.478 us; speedup vs baseline: 5.4033x; 5.4033x over previous
//
#include <hip/hip_runtime.h>
#include <hip/hip_bf16.h>

#define D 128

// ===================== CSR build (counting sort by dst) =====================

__global__ __launch_bounds__(256) void k_hist(const int* __restrict__ dst,
                                              int* __restrict__ cnt, int e) {
    int i = blockIdx.x * 256 + threadIdx.x;
    if (i < e) atomicAdd(&cnt[dst[i]], 1);
}

#define SCAN_CHUNK 1024   // 256 threads x 4 elements

// exclusive scan within each 1024-chunk -> ptr[i]; chunk totals -> sums[b]
__global__ __launch_bounds__(256) void k_scan_local(const int* __restrict__ cnt,
                                                    int* __restrict__ ptr,
                                                    int* __restrict__ sums, int n) {
    __shared__ int tsum[256];
    const int t = threadIdx.x;
    const int base = blockIdx.x * SCAN_CHUNK + t * 4;
    int v[4]; int s = 0;
    #pragma unroll
    for (int i = 0; i < 4; ++i) {
        int idx = base + i;
        v[i] = (idx < n) ? cnt[idx] : 0;
        s += v[i];
    }
    tsum[t] = s;
    __syncthreads();
    for (int off = 1; off < 256; off <<= 1) {
        int x = (t >= off) ? tsum[t - off] : 0;
        __syncthreads();
        tsum[t] += x;
        __syncthreads();
    }
    int run = (t > 0) ? tsum[t - 1] : 0;   // exclusive prefix of this thread
    if (t == 255) sums[blockIdx.x] = tsum[255];
    #pragma unroll
    for (int i = 0; i < 4; ++i) {
        int idx = base + i;
        if (idx < n) ptr[idx] = run;
        run += v[i];
    }
}

// single block: exclusive scan of chunk sums in place (nChunks <= 256)
__global__ __launch_bounds__(256) void k_scan_sums(int* __restrict__ sums, int nChunks) {
    __shared__ int ls[256];
    const int t = threadIdx.x;
    ls[t] = (t < nChunks) ? sums[t] : 0;
    __syncthreads();
    for (int off = 1; off < 256; off <<= 1) {
        int x = (t >= off) ? ls[t - off] : 0;
        __syncthreads();
        ls[t] += x;
        __syncthreads();
    }
    if (t < nChunks) sums[t] = (t > 0) ? ls[t - 1] : 0;   // exclusive
}

// ptr[i] += chunkOff ; also dinv[i] = rsqrt(1 + cnt[i]) ; ptr[n] = E
__global__ __launch_bounds__(256) void k_scan_add(int* __restrict__ ptr,
                                                  const int* __restrict__ sums,
                                                  const int* __restrict__ cnt,
                                                  float* __restrict__ dinv,
                                                  int n, int e) {
    int i = blockIdx.x * 256 + threadIdx.x;
    if (i < n) {
        ptr[i] += sums[i >> 10];
        dinv[i] = rsqrtf((float)(1 + cnt[i]));   // self-loop adds 1
    }
    if (i == 0) ptr[n] = e;
}

__global__ __launch_bounds__(256) void k_fill(const int* __restrict__ src,
                                              const int* __restrict__ dst,
                                              const int* __restrict__ ptr,
                                              int* __restrict__ fill,
                                              int* __restrict__ csr_src, int e) {
    int i = blockIdx.x * 256 + threadIdx.x;
    if (i < e) {
        int d = dst[i];
        int slot = ptr[d] + atomicAdd(&fill[d], 1);
        csr_src[slot] = src[i];
    }
}

// ===================== SGEMM: C[M x 128] = A[M x 128] @ W[128 x 128] (+bias) ====
#define BM 128
#define BN 128
#define BK 16
#define TM 8
#define TN 8

__global__ __launch_bounds__(256) void k_sgemm(const float* __restrict__ A,
                                               const float* __restrict__ W,
                                               const float* __restrict__ bias,
                                               float* __restrict__ C, int M) {
    __shared__ float As[BK][BM];
    __shared__ float Bs[BK][BN];

    const int tid = threadIdx.x;
    const int row0 = blockIdx.x * BM;
    const int tx = tid & 15;
    const int ty = tid >> 4;

    float acc[TM][TN] = {};

    for (int k0 = 0; k0 < D; k0 += BK) {
        #pragma unroll
        for (int i = 0; i < 2; ++i) {
            int r = (tid >> 2) + i * 64;
            int c = (tid & 3) * 4;
            int rr = row0 + r; if (rr >= M) rr = M - 1;
            const float4 v = *(const float4*)(A + (size_t)rr * D + k0 + c);
            As[c + 0][r] = v.x; As[c + 1][r] = v.y; As[c + 2][r] = v.z; As[c + 3][r] = v.w;
        }
        #pragma unroll
        for (int i = 0; i < 2; ++i) {
            int idx = tid + i * 256;
            int rk = idx >> 5;
            int cc = (idx & 31) * 4;
            *(float4*)&Bs[rk][cc] = *(const float4*)(W + (size_t)(k0 + rk) * D + cc);
        }
        __syncthreads();

        #pragma unroll
        for (int kk = 0; kk < BK; ++kk) {
            float a[TM], b[TN];
            #pragma unroll
            for (int i = 0; i < TM; i += 4)
                *(float4*)&a[i] = *(const float4*)&As[kk][ty * TM + i];
            #pragma unroll
            for (int j = 0; j < TN; j += 4)
                *(float4*)&b[j] = *(const float4*)&Bs[kk][tx * TN + j];
            #pragma unroll
            for (int i = 0; i < TM; ++i)
                #pragma unroll
                for (int j = 0; j < TN; ++j)
                    acc[i][j] += a[i] * b[j];
        }
        __syncthreads();
    }

    #pragma unroll
    for (int i = 0; i < TM; ++i) {
        int r = row0 + ty * TM + i;
        if (r >= M) continue;
        #pragma unroll
        for (int j = 0; j < TN; j += 4) {
            int cc = tx * TN + j;
            float4 v = *(float4*)&acc[i][j];
            if (bias) {
                float4 bv = *(const float4*)(bias + cc);
                v.x += bv.x; v.y += bv.y; v.z += bv.z; v.w += bv.w;
            }
            *(float4*)(C + (size_t)r * D + cc) = v;
        }
    }
}

// ===================== fused gather + self + bias + relu (+res) =====================
// 32 lanes per node (float4 each = 128 floats), 8 nodes per 256-thread block.
// out_i = relu( dinv_i * sum_{j in N(i)} dinv_j * h_j + dinv_i^2 * h_i + b ) [+ res_i]
__global__ __launch_bounds__(256) void k_gather(const int* __restrict__ ptr,
                                                const int* __restrict__ csr_src,
                                                const float* __restrict__ dinv,
                                                const float* __restrict__ h,
                                                const float* __restrict__ bias,
                                                const float* __restrict__ res,
                                                float* __restrict__ out, int N) {
    const int g = threadIdx.x >> 5;
    const int lane = threadIdx.x & 31;
    const int i = blockIdx.x * 8 + g;
    if (i >= N) return;

    const int p0 = ptr[i];
    const int p1 = ptr[i + 1];
    const float di = dinv[i];

    float4 acc = {0.f, 0.f, 0.f, 0.f};
    for (int j = p0; j < p1; ++j) {
        const int s = csr_src[j];
        const float c = dinv[s];
        const float4 v = *(const float4*)(h + (size_t)s * D + lane * 4);
        acc.x += v.x * c; acc.y += v.y * c; acc.z += v.z * c; acc.w += v.w * c;
    }

    const float4 hv = *(const float4*)(h + (size_t)i * D + lane * 4);
    const float4 bv = *(const float4*)(bias + lane * 4);
    const float self = di * di;
    float4 o;
    o.x = fmaxf(di * acc.x + self * hv.x + bv.x, 0.0f);
    o.y = fmaxf(di * acc.y + self * hv.y + bv.y, 0.0f);
    o.z = fmaxf(di * acc.z + self * hv.z + bv.z, 0.0f);
    o.w = fmaxf(di * acc.w + self * hv.w + bv.w, 0.0f);
    float* po = out + (size_t)i * D + lane * 4;
    if (res) {
        const float4 rv = *(const float4*)(res + (size_t)i * D + lane * 4);
        o.x += rv.x; o.y += rv.y; o.z += rv.z; o.w += rv.w;
    }
    *(float4*)po = o;
}

// ===================== launch =====================

extern "C" void kernel_launch(void* const* d_in, const int* in_sizes, int n_in,
                              void* d_out, int out_size, void* d_ws, size_t ws_size,
                              hipStream_t stream) {
    const int N = in_sizes[0] / D;     // 100000
    const int E = in_sizes[1] / 2;     // 600000

    const float* x   = (const float*)d_in[0];
    const int*   ei  = (const int*)d_in[1];
    const int*   src = ei;
    const int*   dst = ei + E;
    const float* W1  = (const float*)d_in[2];
    const float* b1  = (const float*)d_in[3];
    const float* W2  = (const float*)d_in[4];
    const float* b2  = (const float*)d_in[5];
    const float* Wfc = (const float*)d_in[6];
    const float* bfc = (const float*)d_in[7];
    float* out = (float*)d_out;

    // ---- workspace layout ----
    char* ws = (char*)d_ws;
    size_t off = 0;
    auto alloc = [&](size_t bytes) { char* p = ws + off; off += (bytes + 255) & ~(size_t)255; return p; };
    float* dinv    = (float*)alloc((size_t)N * 4);
    int*   cnt     = (int*)  alloc((size_t)N * 4);        // histogram, then fill cursor
    int*   ptr     = (int*)  alloc((size_t)(N + 1) * 4);
    int*   sums    = (int*)  alloc(256 * 4);
    int*   csr_src = (int*)  alloc((size_t)E * 4);
    float* h       = (float*)alloc((size_t)N * D * 4);    // gemm output
    float* hb      = (float*)alloc((size_t)N * D * 4);    // gathered/activated

    const int nBlk   = (N + 255) / 256;
    const int eBlk   = (E + 255) / 256;
    const int gBlk   = (N + BM - 1) / BM;
    const int aBlk   = (N + 7) / 8;
    const int nChunks = (N + SCAN_CHUNK - 1) / SCAN_CHUNK;

    // ---- CSR build + dinv ----
    hipMemsetAsync(cnt, 0, (size_t)N * 4, stream);
    k_hist<<<eBlk, 256, 0, stream>>>(dst, cnt, E);
    k_scan_local<<<nChunks, 256, 0, stream>>>(cnt, ptr, sums, N);
    k_scan_sums<<<1, 256, 0, stream>>>(sums, nChunks);
    k_scan_add<<<nBlk, 256, 0, stream>>>(ptr, sums, cnt, dinv, N, E);
    hipMemsetAsync(cnt, 0, (size_t)N * 4, stream);
    k_fill<<<eBlk, 256, 0, stream>>>(src, dst, ptr, cnt, csr_src, E);

    // ---- layer 1 + residual GEMMs ----
    k_sgemm<<<gBlk, 256, 0, stream>>>(x, W1, nullptr, h, N);
    k_sgemm<<<gBlk, 256, 0, stream>>>(x, Wfc, bfc, out, N);

    // ---- layer 1 aggregate (fused norm+self+bias+relu) ----
    k_gather<<<aBlk, 256, 0, stream>>>(ptr, csr_src, dinv, h, b1, nullptr, hb, N);

    // ---- layer 2 GEMM (reuse h) ----
    k_sgemm<<<gBlk, 256, 0, stream>>>(hb, W2, nullptr, h, N);

    // ---- layer 2 aggregate + residual (d_out holds res; read-modify-write per row) ----
    k_gather<<<aBlk, 256, 0, stream>>>(ptr, csr_src, dinv, h, b2, out, out, N);
}

// Round 3
// 405.087 us; speedup vs baseline: 5.9020x; 1.0923x over previous
//
#include <hip/hip_runtime.h>
#include <hip/hip_bf16.h>

#define D 128

typedef __bf16 bf16x8 __attribute__((ext_vector_type(8)));
typedef float f32x16 __attribute__((ext_vector_type(16)));

union U16 { uint4 u; bf16x8 v; };

static __device__ __forceinline__ unsigned short f2bf(float f) {
    unsigned u = __float_as_uint(f);
    unsigned r = (u + 0x7fffu + ((u >> 16) & 1u)) >> 16;   // RNE
    return (unsigned short)r;
}
static __device__ __forceinline__ float bf2f(unsigned short s) {
    return __uint_as_float(((unsigned)s) << 16);
}
static __device__ __forceinline__ float u2f_lo(unsigned x) { return __uint_as_float(x << 16); }
static __device__ __forceinline__ float u2f_hi(unsigned x) { return __uint_as_float(x & 0xffff0000u); }

// ===================== CSR build (counting sort by dst) =====================

__global__ __launch_bounds__(256) void k_hist(const int* __restrict__ dst,
                                              int* __restrict__ cnt, int e) {
    int i = blockIdx.x * 256 + threadIdx.x;
    if (i < e) atomicAdd(&cnt[dst[i]], 1);
}

#define SCAN_CHUNK 1024

__global__ __launch_bounds__(256) void k_scan_local(const int* __restrict__ cnt,
                                                    int* __restrict__ ptr,
                                                    int* __restrict__ sums, int n) {
    __shared__ int tsum[256];
    const int t = threadIdx.x;
    const int base = blockIdx.x * SCAN_CHUNK + t * 4;
    int v[4]; int s = 0;
    #pragma unroll
    for (int i = 0; i < 4; ++i) {
        int idx = base + i;
        v[i] = (idx < n) ? cnt[idx] : 0;
        s += v[i];
    }
    tsum[t] = s;
    __syncthreads();
    for (int off = 1; off < 256; off <<= 1) {
        int x = (t >= off) ? tsum[t - off] : 0;
        __syncthreads();
        tsum[t] += x;
        __syncthreads();
    }
    int run = (t > 0) ? tsum[t - 1] : 0;
    if (t == 255) sums[blockIdx.x] = tsum[255];
    #pragma unroll
    for (int i = 0; i < 4; ++i) {
        int idx = base + i;
        if (idx < n) ptr[idx] = run;
        run += v[i];
    }
}

__global__ __launch_bounds__(256) void k_scan_sums(int* __restrict__ sums, int nChunks) {
    __shared__ int ls[256];
    const int t = threadIdx.x;
    ls[t] = (t < nChunks) ? sums[t] : 0;
    __syncthreads();
    for (int off = 1; off < 256; off <<= 1) {
        int x = (t >= off) ? ls[t - off] : 0;
        __syncthreads();
        ls[t] += x;
        __syncthreads();
    }
    if (t < nChunks) sums[t] = (t > 0) ? ls[t - 1] : 0;
}

__global__ __launch_bounds__(256) void k_scan_add(int* __restrict__ ptr,
                                                  const int* __restrict__ sums,
                                                  const int* __restrict__ cnt,
                                                  float* __restrict__ dinv,
                                                  int n, int e) {
    int i = blockIdx.x * 256 + threadIdx.x;
    if (i < n) {
        ptr[i] += sums[i >> 10];
        dinv[i] = rsqrtf((float)(1 + cnt[i]));
    }
    if (i == 0) ptr[n] = e;
}

__global__ __launch_bounds__(256) void k_fill(const int* __restrict__ src,
                                              const int* __restrict__ dst,
                                              const int* __restrict__ ptr,
                                              int* __restrict__ fill,
                                              int* __restrict__ csr_src, int e) {
    int i = blockIdx.x * 256 + threadIdx.x;
    if (i < e) {
        int d = dst[i];
        int slot = ptr[d] + atomicAdd(&fill[d], 1);
        csr_src[slot] = src[i];
    }
}

// ===================== weight prep: W[k][n] fp32 -> Wt_hi/Wt_lo [n][k] bf16 =====
__global__ __launch_bounds__(256) void k_prep_w(const float* __restrict__ W,
                                                unsigned short* __restrict__ Wh,
                                                unsigned short* __restrict__ Wl) {
    int idx = blockIdx.x * 256 + threadIdx.x;   // 16384
    int k = idx >> 7, n = idx & 127;
    float v = W[k * 128 + n];
    unsigned short h = f2bf(v);
    unsigned short l = f2bf(v - bf2f(h));
    Wh[n * 128 + k] = h;
    Wl[n * 128 + k] = l;
}

// ===================== split-bf16 MFMA GEMM =====================
// C = A @ W via Ah*Bh + Ah*Bl + Al*Bh (3 mfma passes), 32x32x16 bf16 mfma.
// Block: 256 thr = 4 waves; tile 128 rows x 128 cols; wave w -> rows 32w..32w+31.
// out1: bf16 [M][128] (no bias). Optional out2: fp32 [M][128] = A@W2 + bias2.
__global__ __launch_bounds__(256, 2) void k_gemm(
        const float* __restrict__ A,
        const unsigned short* __restrict__ B1h, const unsigned short* __restrict__ B1l,
        const unsigned short* __restrict__ B2h, const unsigned short* __restrict__ B2l,
        const float* __restrict__ bias2,
        unsigned short* __restrict__ out1,
        float* __restrict__ out2,
        int M) {
    __shared__ __align__(16) unsigned short As[2][128][72];   // [plane][row][k], pad->16B-aligned b128

    const int tid = threadIdx.x;
    const int wave = tid >> 6;
    const int lane = tid & 63;
    const int l31 = lane & 31;
    const int quad8 = (lane >> 5) * 8;
    const int row0 = blockIdx.x * 128;
    const int rl = wave * 32 + l31;          // A-frag / C row within tile
    const bool dual = (out2 != nullptr);

    f32x16 acc1[4];
    f32x16 acc2[4];
    #pragma unroll
    for (int nt = 0; nt < 4; ++nt)
        #pragma unroll
        for (int r = 0; r < 16; ++r) { acc1[nt][r] = 0.f; acc2[nt][r] = 0.f; }

    for (int kc = 0; kc < 2; ++kc) {          // two K-chunks of 64
        // ---- stage A chunk: 128 rows x 64 k fp32 -> hi/lo bf16 planes ----
        #pragma unroll
        for (int i = 0; i < 8; ++i) {
            int f = tid + i * 256;            // float4 index over [128][16]
            int r = f >> 4, c4 = (f & 15) * 4;
            int rg = row0 + r; if (rg >= M) rg = M - 1;
            float4 v = *(const float4*)(A + (size_t)rg * D + kc * 64 + c4);
            unsigned short h0 = f2bf(v.x), h1 = f2bf(v.y), h2 = f2bf(v.z), h3 = f2bf(v.w);
            unsigned short l0 = f2bf(v.x - bf2f(h0)), l1 = f2bf(v.y - bf2f(h1));
            unsigned short l2 = f2bf(v.z - bf2f(h2)), l3 = f2bf(v.w - bf2f(h3));
            *(ushort4*)&As[0][r][c4] = (ushort4){h0, h1, h2, h3};
            *(ushort4*)&As[1][r][c4] = (ushort4){l0, l1, l2, l3};
        }
        __syncthreads();

        const int kbase = kc * 64;
        #pragma unroll
        for (int ks = 0; ks < 4; ++ks) {
            const int kk = ks * 16 + quad8;
            U16 ah, al;
            ah.u = *(const uint4*)&As[0][rl][kk];
            al.u = *(const uint4*)&As[1][rl][kk];
            const int kg = kbase + kk;
            #pragma unroll
            for (int nt = 0; nt < 4; ++nt) {
                const size_t bo = (size_t)(nt * 32 + l31) * D + kg;
                U16 bh, bl;
                bh.u = *(const uint4*)(B1h + bo);
                bl.u = *(const uint4*)(B1l + bo);
                acc1[nt] = __builtin_amdgcn_mfma_f32_32x32x16_bf16(ah.v, bh.v, acc1[nt], 0, 0, 0);
                acc1[nt] = __builtin_amdgcn_mfma_f32_32x32x16_bf16(ah.v, bl.v, acc1[nt], 0, 0, 0);
                acc1[nt] = __builtin_amdgcn_mfma_f32_32x32x16_bf16(al.v, bh.v, acc1[nt], 0, 0, 0);
                if (dual) {
                    U16 ch, cl;
                    ch.u = *(const uint4*)(B2h + bo);
                    cl.u = *(const uint4*)(B2l + bo);
                    acc2[nt] = __builtin_amdgcn_mfma_f32_32x32x16_bf16(ah.v, ch.v, acc2[nt], 0, 0, 0);
                    acc2[nt] = __builtin_amdgcn_mfma_f32_32x32x16_bf16(ah.v, cl.v, acc2[nt], 0, 0, 0);
                    acc2[nt] = __builtin_amdgcn_mfma_f32_32x32x16_bf16(al.v, ch.v, acc2[nt], 0, 0, 0);
                }
            }
        }
        __syncthreads();
    }

    // ---- epilogue: C/D layout (verified m74/m101): col=lane&31, row=(reg&3)+8*(reg>>2)+4*(lane>>5)
    #pragma unroll
    for (int nt = 0; nt < 4; ++nt) {
        const int col = nt * 32 + l31;
        const float b2v = dual ? bias2[col] : 0.f;
        #pragma unroll
        for (int reg = 0; reg < 16; ++reg) {
            const int r = wave * 32 + (reg & 3) + 8 * (reg >> 2) + 4 * (lane >> 5);
            const int rg = row0 + r;
            if (rg < M) {
                out1[(size_t)rg * D + col] = f2bf(acc1[nt][reg]);
                if (dual) out2[(size_t)rg * D + col] = acc2[nt][reg] + b2v;
            }
        }
    }
}

// ===================== fused gather (bf16 h) + self + bias + relu (+res) ========
__global__ __launch_bounds__(256) void k_gather_bf(const int* __restrict__ ptr,
                                                   const int* __restrict__ csr_src,
                                                   const float* __restrict__ dinv,
                                                   const unsigned short* __restrict__ h,
                                                   const float* __restrict__ bias,
                                                   const float* __restrict__ res,
                                                   float* __restrict__ out, int N) {
    const int g = threadIdx.x >> 5;
    const int lane = threadIdx.x & 31;
    const int i = blockIdx.x * 8 + g;
    if (i >= N) return;

    const int p0 = ptr[i];
    const int p1 = ptr[i + 1];
    const float di = dinv[i];

    float a0 = 0.f, a1 = 0.f, a2 = 0.f, a3 = 0.f;
    for (int j = p0; j < p1; ++j) {
        const int s = csr_src[j];
        const float c = dinv[s];
        const uint2 u = *(const uint2*)(h + (size_t)s * D + lane * 4);
        a0 = fmaf(c, u2f_lo(u.x), a0);
        a1 = fmaf(c, u2f_hi(u.x), a1);
        a2 = fmaf(c, u2f_lo(u.y), a2);
        a3 = fmaf(c, u2f_hi(u.y), a3);
    }

    const uint2 us = *(const uint2*)(h + (size_t)i * D + lane * 4);
    const float4 bv = *(const float4*)(bias + lane * 4);
    const float self = di * di;
    float4 o;
    o.x = fmaxf(di * a0 + self * u2f_lo(us.x) + bv.x, 0.0f);
    o.y = fmaxf(di * a1 + self * u2f_hi(us.x) + bv.y, 0.0f);
    o.z = fmaxf(di * a2 + self * u2f_lo(us.y) + bv.z, 0.0f);
    o.w = fmaxf(di * a3 + self * u2f_hi(us.y) + bv.w, 0.0f);
    if (res) {
        const float4 rv = *(const float4*)(res + (size_t)i * D + lane * 4);
        o.x += rv.x; o.y += rv.y; o.z += rv.z; o.w += rv.w;
    }
    *(float4*)(out + (size_t)i * D + lane * 4) = o;
}

// ===================== launch =====================

extern "C" void kernel_launch(void* const* d_in, const int* in_sizes, int n_in,
                              void* d_out, int out_size, void* d_ws, size_t ws_size,
                              hipStream_t stream) {
    const int N = in_sizes[0] / D;     // 100000
    const int E = in_sizes[1] / 2;     // 600000

    const float* x   = (const float*)d_in[0];
    const int*   ei  = (const int*)d_in[1];
    const int*   src = ei;
    const int*   dst = ei + E;
    const float* W1  = (const float*)d_in[2];
    const float* b1  = (const float*)d_in[3];
    const float* W2  = (const float*)d_in[4];
    const float* b2  = (const float*)d_in[5];
    const float* Wfc = (const float*)d_in[6];
    const float* bfc = (const float*)d_in[7];
    float* out = (float*)d_out;

    // ---- workspace layout ----
    char* ws = (char*)d_ws;
    size_t off = 0;
    auto alloc = [&](size_t bytes) { char* p = ws + off; off += (bytes + 255) & ~(size_t)255; return p; };
    float* dinv    = (float*)alloc((size_t)N * 4);
    int*   cnt     = (int*)  alloc((size_t)N * 4);
    int*   ptr     = (int*)  alloc((size_t)(N + 1) * 4);
    int*   sums    = (int*)  alloc(256 * 4);
    int*   csr_src = (int*)  alloc((size_t)E * 4);
    unsigned short* W1h = (unsigned short*)alloc(128 * 128 * 2);
    unsigned short* W1l = (unsigned short*)alloc(128 * 128 * 2);
    unsigned short* W2h = (unsigned short*)alloc(128 * 128 * 2);
    unsigned short* W2l = (unsigned short*)alloc(128 * 128 * 2);
    unsigned short* Wfh = (unsigned short*)alloc(128 * 128 * 2);
    unsigned short* Wfl = (unsigned short*)alloc(128 * 128 * 2);
    unsigned short* h   = (unsigned short*)alloc((size_t)N * D * 2);  // bf16 features
    float* hb           = (float*)alloc((size_t)N * D * 4);           // fp32 activations

    const int nBlk   = (N + 255) / 256;
    const int eBlk   = (E + 255) / 256;
    const int gBlk   = (N + 127) / 128;
    const int aBlk   = (N + 7) / 8;
    const int nChunks = (N + SCAN_CHUNK - 1) / SCAN_CHUNK;

    // ---- weight prep (independent) ----
    k_prep_w<<<64, 256, 0, stream>>>(W1, W1h, W1l);
    k_prep_w<<<64, 256, 0, stream>>>(W2, W2h, W2l);
    k_prep_w<<<64, 256, 0, stream>>>(Wfc, Wfh, Wfl);

    // ---- CSR build + dinv ----
    hipMemsetAsync(cnt, 0, (size_t)N * 4, stream);
    k_hist<<<eBlk, 256, 0, stream>>>(dst, cnt, E);
    k_scan_local<<<nChunks, 256, 0, stream>>>(cnt, ptr, sums, N);
    k_scan_sums<<<1, 256, 0, stream>>>(sums, nChunks);
    k_scan_add<<<nBlk, 256, 0, stream>>>(ptr, sums, cnt, dinv, N, E);
    hipMemsetAsync(cnt, 0, (size_t)N * 4, stream);
    k_fill<<<eBlk, 256, 0, stream>>>(src, dst, ptr, cnt, csr_src, E);

    // ---- fused layer-1 + residual GEMMs: h = bf16(x@W1), out = x@Wfc + bfc ----
    k_gemm<<<gBlk, 256, 0, stream>>>(x, W1h, W1l, Wfh, Wfl, bfc, h, out, N);

    // ---- layer 1 aggregate (fused norm+self+bias+relu) ----
    k_gather_bf<<<aBlk, 256, 0, stream>>>(ptr, csr_src, dinv, h, b1, nullptr, hb, N);

    // ---- layer 2 GEMM: h = bf16(hb@W2) ----
    k_gemm<<<gBlk, 256, 0, stream>>>(hb, W2h, W2l, nullptr, nullptr, nullptr, h, nullptr, N);

    // ---- layer 2 aggregate + residual ----
    k_gather_bf<<<aBlk, 256, 0, stream>>>(ptr, csr_src, dinv, h, b2, out, out, N);
}

// Round 4
// 346.047 us; speedup vs baseline: 6.9090x; 1.1706x over previous
//
#include <hip/hip_runtime.h>
#include <hip/hip_bf16.h>

#define D 128

typedef __bf16 bf16x8 __attribute__((ext_vector_type(8)));
typedef float f32x16 __attribute__((ext_vector_type(16)));

union U16 { uint4 u; bf16x8 v; };

static __device__ __forceinline__ unsigned short f2bf(float f) {
    unsigned u = __float_as_uint(f);
    unsigned r = (u + 0x7fffu + ((u >> 16) & 1u)) >> 16;   // RNE
    return (unsigned short)r;
}
static __device__ __forceinline__ float bf2f(unsigned short s) {
    return __uint_as_float(((unsigned)s) << 16);
}
static __device__ __forceinline__ float u2f_lo(unsigned x) { return __uint_as_float(x << 16); }
static __device__ __forceinline__ float u2f_hi(unsigned x) { return __uint_as_float(x & 0xffff0000u); }

// ===================== CSR build (counting sort by dst) =====================

__global__ __launch_bounds__(256) void k_hist(const int* __restrict__ dst,
                                              int* __restrict__ cnt, int e) {
    int i = blockIdx.x * 256 + threadIdx.x;
    if (i < e) atomicAdd(&cnt[dst[i]], 1);
}

#define SCAN_CHUNK 1024

__global__ __launch_bounds__(256) void k_scan_local(const int* __restrict__ cnt,
                                                    int* __restrict__ ptr,
                                                    int* __restrict__ sums, int n) {
    __shared__ int tsum[256];
    const int t = threadIdx.x;
    const int base = blockIdx.x * SCAN_CHUNK + t * 4;
    int v[4]; int s = 0;
    #pragma unroll
    for (int i = 0; i < 4; ++i) {
        int idx = base + i;
        v[i] = (idx < n) ? cnt[idx] : 0;
        s += v[i];
    }
    tsum[t] = s;
    __syncthreads();
    for (int off = 1; off < 256; off <<= 1) {
        int x = (t >= off) ? tsum[t - off] : 0;
        __syncthreads();
        tsum[t] += x;
        __syncthreads();
    }
    int run = (t > 0) ? tsum[t - 1] : 0;
    if (t == 255) sums[blockIdx.x] = tsum[255];
    #pragma unroll
    for (int i = 0; i < 4; ++i) {
        int idx = base + i;
        if (idx < n) ptr[idx] = run;
        run += v[i];
    }
}

__global__ __launch_bounds__(256) void k_scan_sums(int* __restrict__ sums, int nChunks) {
    __shared__ int ls[256];
    const int t = threadIdx.x;
    ls[t] = (t < nChunks) ? sums[t] : 0;
    __syncthreads();
    for (int off = 1; off < 256; off <<= 1) {
        int x = (t >= off) ? ls[t - off] : 0;
        __syncthreads();
        ls[t] += x;
        __syncthreads();
    }
    if (t < nChunks) sums[t] = (t > 0) ? ls[t - 1] : 0;
}

__global__ __launch_bounds__(256) void k_scan_add(int* __restrict__ ptr,
                                                  const int* __restrict__ sums,
                                                  const int* __restrict__ cnt,
                                                  float* __restrict__ dinv,
                                                  int n, int e) {
    int i = blockIdx.x * 256 + threadIdx.x;
    if (i < n) {
        ptr[i] += sums[i >> 10];
        dinv[i] = rsqrtf((float)(1 + cnt[i]));
    }
    if (i == 0) ptr[n] = e;
}

__global__ __launch_bounds__(256) void k_fill(const int* __restrict__ src,
                                              const int* __restrict__ dst,
                                              const int* __restrict__ ptr,
                                              int* __restrict__ fill,
                                              int* __restrict__ csr_src, int e) {
    int i = blockIdx.x * 256 + threadIdx.x;
    if (i < e) {
        int d = dst[i];
        int slot = ptr[d] + atomicAdd(&fill[d], 1);
        csr_src[slot] = src[i];
    }
}

// ===================== weight prep: W[k][n] fp32 -> Wt_hi/Wt_lo [n][k] bf16 =====
__global__ __launch_bounds__(256) void k_prep_w(const float* __restrict__ W,
                                                unsigned short* __restrict__ Wh,
                                                unsigned short* __restrict__ Wl) {
    int idx = blockIdx.x * 256 + threadIdx.x;   // 16384
    int k = idx >> 7, n = idx & 127;
    float v = W[k * 128 + n];
    unsigned short h = f2bf(v);
    unsigned short l = f2bf(v - bf2f(h));
    Wh[n * 128 + k] = h;
    Wl[n * 128 + k] = l;
}

// ===================== register-resident-B split-bf16 MFMA GEMM ================
// C[M x 128] = A[M x 128] @ W. Each block: 4 waves; wave w owns cols 32w..32w+31
// with hi/lo B fragments (full K) in 64 VGPRs, loaded ONCE. Grid-stride over
// 32-row tiles; A staged fp32->hi/lo bf16 via LDS (padded stride, ds_read_b128).
// Mode A (outb!=0): bf16 out, no bias. Mode B (outf!=0): fp32 out + bias.
#define APAD 136   // 128 + 8 bf16 pad: 272 B row stride, 16B-aligned, 4-way b128 conflict only

__global__ __launch_bounds__(256, 4) void k_gemm_rr(
        const float* __restrict__ A,
        const unsigned short* __restrict__ Bh, const unsigned short* __restrict__ Bl,
        const float* __restrict__ bias,
        unsigned short* __restrict__ outb,
        float* __restrict__ outf,
        int M, int nTiles) {
    __shared__ __align__(16) unsigned short As[2][32][APAD];

    const int tid = threadIdx.x;
    const int wave = tid >> 6;
    const int lane = tid & 63;
    const int l31 = lane & 31;
    const int quad8 = (lane >> 5) * 8;
    const int col = wave * 32 + l31;

    // ---- preload this wave's B fragments (hi+lo, full K=128): 64 VGPRs ----
    U16 bh[8], bl[8];
    #pragma unroll
    for (int ks = 0; ks < 8; ++ks) {
        const size_t bo = (size_t)col * D + ks * 16 + quad8;
        bh[ks].u = *(const uint4*)(Bh + bo);
        bl[ks].u = *(const uint4*)(Bl + bo);
    }
    const float bv = (bias != nullptr) ? bias[col] : 0.f;

    for (int t = blockIdx.x; t < nTiles; t += gridDim.x) {
        const int row0 = t * 32;

        // ---- stage A tile: 32 rows x 128 k, fp32 -> hi/lo bf16 (coalesced) ----
        #pragma unroll
        for (int i = 0; i < 4; ++i) {
            int f = tid + i * 256;            // float4 index over [32][32]
            int r = f >> 5, c4 = (f & 31) * 4;
            int rg = row0 + r; if (rg >= M) rg = M - 1;
            float4 v = *(const float4*)(A + (size_t)rg * D + c4);
            ushort4 hq, lq;
            hq.x = f2bf(v.x); hq.y = f2bf(v.y); hq.z = f2bf(v.z); hq.w = f2bf(v.w);
            lq.x = f2bf(v.x - bf2f(hq.x)); lq.y = f2bf(v.y - bf2f(hq.y));
            lq.z = f2bf(v.z - bf2f(hq.z)); lq.w = f2bf(v.w - bf2f(hq.w));
            *(ushort4*)&As[0][r][c4] = hq;
            *(ushort4*)&As[1][r][c4] = lq;
        }
        __syncthreads();

        f32x16 acc;
        #pragma unroll
        for (int r = 0; r < 16; ++r) acc[r] = 0.f;

        #pragma unroll
        for (int ks = 0; ks < 8; ++ks) {
            U16 ah, al;
            ah.u = *(const uint4*)&As[0][l31][ks * 16 + quad8];
            al.u = *(const uint4*)&As[1][l31][ks * 16 + quad8];
            acc = __builtin_amdgcn_mfma_f32_32x32x16_bf16(ah.v, bh[ks].v, acc, 0, 0, 0);
            acc = __builtin_amdgcn_mfma_f32_32x32x16_bf16(ah.v, bl[ks].v, acc, 0, 0, 0);
            acc = __builtin_amdgcn_mfma_f32_32x32x16_bf16(al.v, bh[ks].v, acc, 0, 0, 0);
        }
        __syncthreads();

        // ---- epilogue: C/D layout col=lane&31, row=(reg&3)+8*(reg>>2)+4*(lane>>5)
        #pragma unroll
        for (int reg = 0; reg < 16; ++reg) {
            const int r = (reg & 3) + 8 * (reg >> 2) + 4 * (lane >> 5);
            const int rg = row0 + r;
            if (rg < M) {
                if (outb) outb[(size_t)rg * D + col] = f2bf(acc[reg]);
                else      outf[(size_t)rg * D + col] = acc[reg] + bv;
            }
        }
    }
}

// ===================== fused gather (bf16 h) + self + bias + relu (+res) ========
__global__ __launch_bounds__(256) void k_gather_bf(const int* __restrict__ ptr,
                                                   const int* __restrict__ csr_src,
                                                   const float* __restrict__ dinv,
                                                   const unsigned short* __restrict__ h,
                                                   const float* __restrict__ bias,
                                                   const float* __restrict__ res,
                                                   float* __restrict__ out, int N) {
    const int g = threadIdx.x >> 5;
    const int lane = threadIdx.x & 31;
    const int i = blockIdx.x * 8 + g;
    if (i >= N) return;

    const int p0 = ptr[i];
    const int p1 = ptr[i + 1];
    const float di = dinv[i];

    float a0 = 0.f, a1 = 0.f, a2 = 0.f, a3 = 0.f;
    for (int j = p0; j < p1; ++j) {
        const int s = csr_src[j];
        const float c = dinv[s];
        const uint2 u = *(const uint2*)(h + (size_t)s * D + lane * 4);
        a0 = fmaf(c, u2f_lo(u.x), a0);
        a1 = fmaf(c, u2f_hi(u.x), a1);
        a2 = fmaf(c, u2f_lo(u.y), a2);
        a3 = fmaf(c, u2f_hi(u.y), a3);
    }

    const uint2 us = *(const uint2*)(h + (size_t)i * D + lane * 4);
    const float4 bv = *(const float4*)(bias + lane * 4);
    const float self = di * di;
    float4 o;
    o.x = fmaxf(di * a0 + self * u2f_lo(us.x) + bv.x, 0.0f);
    o.y = fmaxf(di * a1 + self * u2f_hi(us.x) + bv.y, 0.0f);
    o.z = fmaxf(di * a2 + self * u2f_lo(us.y) + bv.z, 0.0f);
    o.w = fmaxf(di * a3 + self * u2f_hi(us.y) + bv.w, 0.0f);
    if (res) {
        const float4 rv = *(const float4*)(res + (size_t)i * D + lane * 4);
        o.x += rv.x; o.y += rv.y; o.z += rv.z; o.w += rv.w;
    }
    *(float4*)(out + (size_t)i * D + lane * 4) = o;
}

// ===================== launch =====================

extern "C" void kernel_launch(void* const* d_in, const int* in_sizes, int n_in,
                              void* d_out, int out_size, void* d_ws, size_t ws_size,
                              hipStream_t stream) {
    const int N = in_sizes[0] / D;     // 100000
    const int E = in_sizes[1] / 2;     // 600000

    const float* x   = (const float*)d_in[0];
    const int*   ei  = (const int*)d_in[1];
    const int*   src = ei;
    const int*   dst = ei + E;
    const float* W1  = (const float*)d_in[2];
    const float* b1  = (const float*)d_in[3];
    const float* W2  = (const float*)d_in[4];
    const float* b2  = (const float*)d_in[5];
    const float* Wfc = (const float*)d_in[6];
    const float* bfc = (const float*)d_in[7];
    float* out = (float*)d_out;

    // ---- workspace layout ----
    char* ws = (char*)d_ws;
    size_t off = 0;
    auto alloc = [&](size_t bytes) { char* p = ws + off; off += (bytes + 255) & ~(size_t)255; return p; };
    float* dinv    = (float*)alloc((size_t)N * 4);
    int*   cnt     = (int*)  alloc((size_t)N * 4);
    int*   ptr     = (int*)  alloc((size_t)(N + 1) * 4);
    int*   sums    = (int*)  alloc(256 * 4);
    int*   csr_src = (int*)  alloc((size_t)E * 4);
    unsigned short* W1h = (unsigned short*)alloc(128 * 128 * 2);
    unsigned short* W1l = (unsigned short*)alloc(128 * 128 * 2);
    unsigned short* W2h = (unsigned short*)alloc(128 * 128 * 2);
    unsigned short* W2l = (unsigned short*)alloc(128 * 128 * 2);
    unsigned short* Wfh = (unsigned short*)alloc(128 * 128 * 2);
    unsigned short* Wfl = (unsigned short*)alloc(128 * 128 * 2);
    unsigned short* h   = (unsigned short*)alloc((size_t)N * D * 2);  // bf16 features
    float* hb           = (float*)alloc((size_t)N * D * 4);           // fp32 activations

    const int nBlk    = (N + 255) / 256;
    const int eBlk    = (E + 255) / 256;
    const int aBlk    = (N + 7) / 8;
    const int nChunks = (N + SCAN_CHUNK - 1) / SCAN_CHUNK;
    const int nTiles  = (N + 31) / 32;
    const int gBlk    = nTiles < 1024 ? nTiles : 1024;   // 4 blocks/CU resident

    // ---- weight prep ----
    k_prep_w<<<64, 256, 0, stream>>>(W1, W1h, W1l);
    k_prep_w<<<64, 256, 0, stream>>>(W2, W2h, W2l);
    k_prep_w<<<64, 256, 0, stream>>>(Wfc, Wfh, Wfl);

    // ---- CSR build + dinv ----
    hipMemsetAsync(cnt, 0, (size_t)N * 4, stream);
    k_hist<<<eBlk, 256, 0, stream>>>(dst, cnt, E);
    k_scan_local<<<nChunks, 256, 0, stream>>>(cnt, ptr, sums, N);
    k_scan_sums<<<1, 256, 0, stream>>>(sums, nChunks);
    k_scan_add<<<nBlk, 256, 0, stream>>>(ptr, sums, cnt, dinv, N, E);
    hipMemsetAsync(cnt, 0, (size_t)N * 4, stream);
    k_fill<<<eBlk, 256, 0, stream>>>(src, dst, ptr, cnt, csr_src, E);

    // ---- h = bf16(x@W1) ; out = x@Wfc + bfc (x is L3-resident after 1st pass) ----
    k_gemm_rr<<<gBlk, 256, 0, stream>>>(x, W1h, W1l, nullptr, h, nullptr, N, nTiles);
    k_gemm_rr<<<gBlk, 256, 0, stream>>>(x, Wfh, Wfl, bfc, nullptr, out, N, nTiles);

    // ---- layer 1 aggregate (fused norm+self+bias+relu) ----
    k_gather_bf<<<aBlk, 256, 0, stream>>>(ptr, csr_src, dinv, h, b1, nullptr, hb, N);

    // ---- h = bf16(hb@W2) ----
    k_gemm_rr<<<gBlk, 256, 0, stream>>>(hb, W2h, W2l, nullptr, h, nullptr, N, nTiles);

    // ---- layer 2 aggregate + residual ----
    k_gather_bf<<<aBlk, 256, 0, stream>>>(ptr, csr_src, dinv, h, b2, out, out, N);
}

// Round 5
// 304.601 us; speedup vs baseline: 7.8491x; 1.1361x over previous
//
#include <hip/hip_runtime.h>
#include <hip/hip_bf16.h>

#define D 128

typedef __bf16 bf16x8 __attribute__((ext_vector_type(8)));
typedef float f32x16 __attribute__((ext_vector_type(16)));

union U16 { uint4 u; bf16x8 v; };

static __device__ __forceinline__ unsigned short f2bf(float f) {
    unsigned u = __float_as_uint(f);
    unsigned r = (u + 0x7fffu + ((u >> 16) & 1u)) >> 16;   // RNE
    return (unsigned short)r;
}
static __device__ __forceinline__ float bf2f(unsigned short s) {
    return __uint_as_float(((unsigned)s) << 16);
}
static __device__ __forceinline__ float u2f_lo(unsigned x) { return __uint_as_float(x << 16); }
static __device__ __forceinline__ float u2f_hi(unsigned x) { return __uint_as_float(x & 0xffff0000u); }

// ===================== fused weight prep (3 matrices) + cnt zero =====================
// W[k][n] fp32 -> hi/lo bf16 planes transposed to [n][k]; also zeroes cnt[0..n).
__global__ __launch_bounds__(256) void k_prep(
        const float* __restrict__ W1, const float* __restrict__ W2, const float* __restrict__ Wf,
        unsigned short* __restrict__ W1h, unsigned short* __restrict__ W1l,
        unsigned short* __restrict__ W2h, unsigned short* __restrict__ W2l,
        unsigned short* __restrict__ Wfh, unsigned short* __restrict__ Wfl,
        int* __restrict__ cnt, int n) {
    int idx = blockIdx.x * 256 + threadIdx.x;
    if (idx < 3 * 16384) {
        int which = idx >> 14;
        int local = idx & 16383;
        int k = local >> 7, c = local & 127;
        const float* W = (which == 0) ? W1 : (which == 1) ? W2 : Wf;
        unsigned short* Wh = (which == 0) ? W1h : (which == 1) ? W2h : Wfh;
        unsigned short* Wl = (which == 0) ? W1l : (which == 1) ? W2l : Wfl;
        float v = W[k * 128 + c];
        unsigned short h = f2bf(v);
        unsigned short l = f2bf(v - bf2f(h));
        Wh[c * 128 + k] = h;
        Wl[c * 128 + k] = l;
    }
    if (idx < n) cnt[idx] = 0;
}

// ===================== CSR build (counting sort by dst) =====================

__global__ __launch_bounds__(256) void k_hist(const int* __restrict__ dst,
                                              int* __restrict__ cnt, int e) {
    int i = blockIdx.x * 256 + threadIdx.x;
    if (i < e) atomicAdd(&cnt[dst[i]], 1);
}

#define SCAN_CHUNK 1024

__global__ __launch_bounds__(256) void k_scan_local(const int* __restrict__ cnt,
                                                    int* __restrict__ ptr,
                                                    int* __restrict__ sums, int n) {
    __shared__ int tsum[256];
    const int t = threadIdx.x;
    const int base = blockIdx.x * SCAN_CHUNK + t * 4;
    int v[4]; int s = 0;
    #pragma unroll
    for (int i = 0; i < 4; ++i) {
        int idx = base + i;
        v[i] = (idx < n) ? cnt[idx] : 0;
        s += v[i];
    }
    tsum[t] = s;
    __syncthreads();
    for (int off = 1; off < 256; off <<= 1) {
        int x = (t >= off) ? tsum[t - off] : 0;
        __syncthreads();
        tsum[t] += x;
        __syncthreads();
    }
    int run = (t > 0) ? tsum[t - 1] : 0;
    if (t == 255) sums[blockIdx.x] = tsum[255];
    #pragma unroll
    for (int i = 0; i < 4; ++i) {
        int idx = base + i;
        if (idx < n) ptr[idx] = run;
        run += v[i];
    }
}

__global__ __launch_bounds__(256) void k_scan_sums(int* __restrict__ sums, int nChunks) {
    __shared__ int ls[256];
    const int t = threadIdx.x;
    ls[t] = (t < nChunks) ? sums[t] : 0;
    __syncthreads();
    for (int off = 1; off < 256; off <<= 1) {
        int x = (t >= off) ? ls[t - off] : 0;
        __syncthreads();
        ls[t] += x;
        __syncthreads();
    }
    if (t < nChunks) sums[t] = (t > 0) ? ls[t - 1] : 0;
}

// ptr += chunk offset; dinv = rsqrt(1+cnt); cnt -> 0 (fill cursor); ptr[n] = E
__global__ __launch_bounds__(256) void k_scan_add(int* __restrict__ ptr,
                                                  const int* __restrict__ sums,
                                                  int* __restrict__ cnt,
                                                  float* __restrict__ dinv,
                                                  int n, int e) {
    int i = blockIdx.x * 256 + threadIdx.x;
    if (i < n) {
        ptr[i] += sums[i >> 10];
        dinv[i] = rsqrtf((float)(1 + cnt[i]));
        cnt[i] = 0;
    }
    if (i == 0) ptr[n] = e;
}

__global__ __launch_bounds__(256) void k_fill(const int* __restrict__ src,
                                              const int* __restrict__ dst,
                                              const int* __restrict__ ptr,
                                              int* __restrict__ fill,
                                              int* __restrict__ csr_src, int e) {
    int i = blockIdx.x * 256 + threadIdx.x;
    if (i < e) {
        int d = dst[i];
        int slot = ptr[d] + atomicAdd(&fill[d], 1);
        csr_src[slot] = src[i];
    }
}

// ===================== register-resident-B split-bf16 MFMA GEMM (fp32 A) ========
#define APAD 136   // 128 + 8 bf16 pad: 272 B stride, 16B-aligned

__global__ __launch_bounds__(256, 4) void k_gemm_rr(
        const float* __restrict__ A,
        const unsigned short* __restrict__ Bh, const unsigned short* __restrict__ Bl,
        const float* __restrict__ bias,
        unsigned short* __restrict__ outb,
        float* __restrict__ outf,
        int M, int nTiles) {
    __shared__ __align__(16) unsigned short As[2][32][APAD];

    const int tid = threadIdx.x;
    const int wave = tid >> 6;
    const int lane = tid & 63;
    const int l31 = lane & 31;
    const int quad8 = (lane >> 5) * 8;
    const int col = wave * 32 + l31;

    U16 bh[8], bl[8];
    #pragma unroll
    for (int ks = 0; ks < 8; ++ks) {
        const size_t bo = (size_t)col * D + ks * 16 + quad8;
        bh[ks].u = *(const uint4*)(Bh + bo);
        bl[ks].u = *(const uint4*)(Bl + bo);
    }
    const float bv = (bias != nullptr) ? bias[col] : 0.f;

    for (int t = blockIdx.x; t < nTiles; t += gridDim.x) {
        const int row0 = t * 32;

        #pragma unroll
        for (int i = 0; i < 4; ++i) {
            int f = tid + i * 256;            // float4 index over [32][32]
            int r = f >> 5, c4 = (f & 31) * 4;
            int rg = row0 + r; if (rg >= M) rg = M - 1;
            float4 v = *(const float4*)(A + (size_t)rg * D + c4);
            ushort4 hq, lq;
            hq.x = f2bf(v.x); hq.y = f2bf(v.y); hq.z = f2bf(v.z); hq.w = f2bf(v.w);
            lq.x = f2bf(v.x - bf2f(hq.x)); lq.y = f2bf(v.y - bf2f(hq.y));
            lq.z = f2bf(v.z - bf2f(hq.z)); lq.w = f2bf(v.w - bf2f(hq.w));
            *(ushort4*)&As[0][r][c4] = hq;
            *(ushort4*)&As[1][r][c4] = lq;
        }
        __syncthreads();

        f32x16 acc;
        #pragma unroll
        for (int r = 0; r < 16; ++r) acc[r] = 0.f;

        #pragma unroll
        for (int ks = 0; ks < 8; ++ks) {
            U16 ah, al;
            ah.u = *(const uint4*)&As[0][l31][ks * 16 + quad8];
            al.u = *(const uint4*)&As[1][l31][ks * 16 + quad8];
            acc = __builtin_amdgcn_mfma_f32_32x32x16_bf16(ah.v, bh[ks].v, acc, 0, 0, 0);
            acc = __builtin_amdgcn_mfma_f32_32x32x16_bf16(ah.v, bl[ks].v, acc, 0, 0, 0);
            acc = __builtin_amdgcn_mfma_f32_32x32x16_bf16(al.v, bh[ks].v, acc, 0, 0, 0);
        }
        __syncthreads();

        #pragma unroll
        for (int reg = 0; reg < 16; ++reg) {
            const int r = (reg & 3) + 8 * (reg >> 2) + 4 * (lane >> 5);
            const int rg = row0 + r;
            if (rg < M) {
                if (outb) outb[(size_t)rg * D + col] = f2bf(acc[reg]);
                else      outf[(size_t)rg * D + col] = acc[reg] + bv;
            }
        }
    }
}

// ===================== register-resident-B GEMM, bf16 A (2 MFMA/k-step) ========
__global__ __launch_bounds__(256, 4) void k_gemm_rr_bf(
        const unsigned short* __restrict__ A,
        const unsigned short* __restrict__ Bh, const unsigned short* __restrict__ Bl,
        unsigned short* __restrict__ outb,
        int M, int nTiles) {
    __shared__ __align__(16) unsigned short As[32][APAD];

    const int tid = threadIdx.x;
    const int wave = tid >> 6;
    const int lane = tid & 63;
    const int l31 = lane & 31;
    const int quad8 = (lane >> 5) * 8;
    const int col = wave * 32 + l31;

    U16 bh[8], bl[8];
    #pragma unroll
    for (int ks = 0; ks < 8; ++ks) {
        const size_t bo = (size_t)col * D + ks * 16 + quad8;
        bh[ks].u = *(const uint4*)(Bh + bo);
        bl[ks].u = *(const uint4*)(Bl + bo);
    }

    for (int t = blockIdx.x; t < nTiles; t += gridDim.x) {
        const int row0 = t * 32;

        // stage 32 rows x 128 bf16 = 512 uint4; 2 per thread
        #pragma unroll
        for (int i = 0; i < 2; ++i) {
            int f = tid + i * 256;            // uint4 index over [32][16]
            int r = f >> 4, c8 = (f & 15) * 8;
            int rg = row0 + r; if (rg >= M) rg = M - 1;
            *(uint4*)&As[r][c8] = *(const uint4*)(A + (size_t)rg * D + c8);
        }
        __syncthreads();

        f32x16 acc;
        #pragma unroll
        for (int r = 0; r < 16; ++r) acc[r] = 0.f;

        #pragma unroll
        for (int ks = 0; ks < 8; ++ks) {
            U16 ah;
            ah.u = *(const uint4*)&As[l31][ks * 16 + quad8];
            acc = __builtin_amdgcn_mfma_f32_32x32x16_bf16(ah.v, bh[ks].v, acc, 0, 0, 0);
            acc = __builtin_amdgcn_mfma_f32_32x32x16_bf16(ah.v, bl[ks].v, acc, 0, 0, 0);
        }
        __syncthreads();

        #pragma unroll
        for (int reg = 0; reg < 16; ++reg) {
            const int r = (reg & 3) + 8 * (reg >> 2) + 4 * (lane >> 5);
            const int rg = row0 + r;
            if (rg < M) outb[(size_t)rg * D + col] = f2bf(acc[reg]);
        }
    }
}

// ===================== fused gather (bf16 h), 4-wide unrolled ===================
// out_i = relu( di*sum dinv_s*h_s + di^2*h_i + b ) [+ res_i]; out fp32 or bf16.
__global__ __launch_bounds__(256) void k_gather_bf(const int* __restrict__ ptr,
                                                   const int* __restrict__ csr_src,
                                                   const float* __restrict__ dinv,
                                                   const unsigned short* __restrict__ h,
                                                   const float* __restrict__ bias,
                                                   const float* __restrict__ res,
                                                   float* __restrict__ outf,
                                                   unsigned short* __restrict__ outb,
                                                   int N) {
    const int g = threadIdx.x >> 5;
    const int lane = threadIdx.x & 31;
    const int i = blockIdx.x * 8 + g;
    if (i >= N) return;

    const int p0 = ptr[i];
    const int p1 = ptr[i + 1];
    const float di = dinv[i];

    float a0 = 0.f, a1 = 0.f, a2 = 0.f, a3 = 0.f;
    int j = p0;
    for (; j + 4 <= p1; j += 4) {
        const int s0 = csr_src[j + 0];
        const int s1 = csr_src[j + 1];
        const int s2 = csr_src[j + 2];
        const int s3 = csr_src[j + 3];
        const float c0 = dinv[s0], c1 = dinv[s1], c2 = dinv[s2], c3 = dinv[s3];
        const uint2 u0 = *(const uint2*)(h + (size_t)s0 * D + lane * 4);
        const uint2 u1 = *(const uint2*)(h + (size_t)s1 * D + lane * 4);
        const uint2 u2 = *(const uint2*)(h + (size_t)s2 * D + lane * 4);
        const uint2 u3 = *(const uint2*)(h + (size_t)s3 * D + lane * 4);
        a0 = fmaf(c0, u2f_lo(u0.x), a0); a1 = fmaf(c0, u2f_hi(u0.x), a1);
        a2 = fmaf(c0, u2f_lo(u0.y), a2); a3 = fmaf(c0, u2f_hi(u0.y), a3);
        a0 = fmaf(c1, u2f_lo(u1.x), a0); a1 = fmaf(c1, u2f_hi(u1.x), a1);
        a2 = fmaf(c1, u2f_lo(u1.y), a2); a3 = fmaf(c1, u2f_hi(u1.y), a3);
        a0 = fmaf(c2, u2f_lo(u2.x), a0); a1 = fmaf(c2, u2f_hi(u2.x), a1);
        a2 = fmaf(c2, u2f_lo(u2.y), a2); a3 = fmaf(c2, u2f_hi(u2.y), a3);
        a0 = fmaf(c3, u2f_lo(u3.x), a0); a1 = fmaf(c3, u2f_hi(u3.x), a1);
        a2 = fmaf(c3, u2f_lo(u3.y), a2); a3 = fmaf(c3, u2f_hi(u3.y), a3);
    }
    for (; j < p1; ++j) {
        const int s = csr_src[j];
        const float c = dinv[s];
        const uint2 u = *(const uint2*)(h + (size_t)s * D + lane * 4);
        a0 = fmaf(c, u2f_lo(u.x), a0);
        a1 = fmaf(c, u2f_hi(u.x), a1);
        a2 = fmaf(c, u2f_lo(u.y), a2);
        a3 = fmaf(c, u2f_hi(u.y), a3);
    }

    const uint2 us = *(const uint2*)(h + (size_t)i * D + lane * 4);
    const float4 bv = *(const float4*)(bias + lane * 4);
    const float self = di * di;
    float o0 = fmaxf(di * a0 + self * u2f_lo(us.x) + bv.x, 0.0f);
    float o1 = fmaxf(di * a1 + self * u2f_hi(us.x) + bv.y, 0.0f);
    float o2 = fmaxf(di * a2 + self * u2f_lo(us.y) + bv.z, 0.0f);
    float o3 = fmaxf(di * a3 + self * u2f_hi(us.y) + bv.w, 0.0f);
    if (outb) {
        ushort4 q = {f2bf(o0), f2bf(o1), f2bf(o2), f2bf(o3)};
        *(ushort4*)(outb + (size_t)i * D + lane * 4) = q;
    } else {
        if (res) {
            const float4 rv = *(const float4*)(res + (size_t)i * D + lane * 4);
            o0 += rv.x; o1 += rv.y; o2 += rv.z; o3 += rv.w;
        }
        float4 o = {o0, o1, o2, o3};
        *(float4*)(outf + (size_t)i * D + lane * 4) = o;
    }
}

// ===================== launch =====================

extern "C" void kernel_launch(void* const* d_in, const int* in_sizes, int n_in,
                              void* d_out, int out_size, void* d_ws, size_t ws_size,
                              hipStream_t stream) {
    const int N = in_sizes[0] / D;     // 100000
    const int E = in_sizes[1] / 2;     // 600000

    const float* x   = (const float*)d_in[0];
    const int*   ei  = (const int*)d_in[1];
    const int*   src = ei;
    const int*   dst = ei + E;
    const float* W1  = (const float*)d_in[2];
    const float* b1  = (const float*)d_in[3];
    const float* W2  = (const float*)d_in[4];
    const float* b2  = (const float*)d_in[5];
    const float* Wfc = (const float*)d_in[6];
    const float* bfc = (const float*)d_in[7];
    float* out = (float*)d_out;

    // ---- workspace layout ----
    char* ws = (char*)d_ws;
    size_t off = 0;
    auto alloc = [&](size_t bytes) { char* p = ws + off; off += (bytes + 255) & ~(size_t)255; return p; };
    float* dinv    = (float*)alloc((size_t)N * 4);
    int*   cnt     = (int*)  alloc((size_t)N * 4);
    int*   ptr     = (int*)  alloc((size_t)(N + 1) * 4);
    int*   sums    = (int*)  alloc(256 * 4);
    int*   csr_src = (int*)  alloc((size_t)E * 4);
    unsigned short* W1h = (unsigned short*)alloc(128 * 128 * 2);
    unsigned short* W1l = (unsigned short*)alloc(128 * 128 * 2);
    unsigned short* W2h = (unsigned short*)alloc(128 * 128 * 2);
    unsigned short* W2l = (unsigned short*)alloc(128 * 128 * 2);
    unsigned short* Wfh = (unsigned short*)alloc(128 * 128 * 2);
    unsigned short* Wfl = (unsigned short*)alloc(128 * 128 * 2);
    unsigned short* h    = (unsigned short*)alloc((size_t)N * D * 2);  // bf16 features
    unsigned short* hb16 = (unsigned short*)alloc((size_t)N * D * 2);  // bf16 activations

    const int nBlk    = (N + 255) / 256;
    const int eBlk    = (E + 255) / 256;
    const int aBlk    = (N + 7) / 8;
    const int nChunks = (N + SCAN_CHUNK - 1) / SCAN_CHUNK;
    const int nTiles  = (N + 31) / 32;
    const int gBlk    = nTiles < 1024 ? nTiles : 1024;
    const int pBlk    = (nBlk > 192) ? nBlk : 192;

    // ---- weight prep + cnt zero (one dispatch) ----
    k_prep<<<pBlk, 256, 0, stream>>>(W1, W2, Wfc, W1h, W1l, W2h, W2l, Wfh, Wfl, cnt, N);

    // ---- CSR build + dinv ----
    k_hist<<<eBlk, 256, 0, stream>>>(dst, cnt, E);
    k_scan_local<<<nChunks, 256, 0, stream>>>(cnt, ptr, sums, N);
    k_scan_sums<<<1, 256, 0, stream>>>(sums, nChunks);
    k_scan_add<<<nBlk, 256, 0, stream>>>(ptr, sums, cnt, dinv, N, E);
    k_fill<<<eBlk, 256, 0, stream>>>(src, dst, ptr, cnt, csr_src, E);

    // ---- h = bf16(x@W1) ; out = x@Wfc + bfc ----
    k_gemm_rr<<<gBlk, 256, 0, stream>>>(x, W1h, W1l, nullptr, h, nullptr, N, nTiles);
    k_gemm_rr<<<gBlk, 256, 0, stream>>>(x, Wfh, Wfl, bfc, nullptr, out, N, nTiles);

    // ---- layer 1 aggregate -> bf16 activations ----
    k_gather_bf<<<aBlk, 256, 0, stream>>>(ptr, csr_src, dinv, h, b1, nullptr, nullptr, hb16, N);

    // ---- h = bf16(hb16@W2), bf16 A path ----
    k_gemm_rr_bf<<<gBlk, 256, 0, stream>>>(hb16, W2h, W2l, h, N, nTiles);

    // ---- layer 2 aggregate + residual -> fp32 out ----
    k_gather_bf<<<aBlk, 256, 0, stream>>>(ptr, csr_src, dinv, h, b2, out, out, nullptr, N);
}